// Round 8
// baseline (387.397 us; speedup 1.0000x reference)
//
#include <hip/hip_runtime.h>

// Problem constants: B=2, L=2048, D=1024, H=16, DH=64, BH=B*H=32, M=B*L=4096
// SCALE = DH^-0.5 = 0.125 (folded into Q at projection time)

typedef __attribute__((ext_vector_type(8))) short short8;
typedef __attribute__((ext_vector_type(8))) __bf16 bf16x8;
typedef __attribute__((ext_vector_type(4))) float f32x4;

#define GLDS16(gp, lp)                                                         \
  __builtin_amdgcn_global_load_lds(                                            \
      (const __attribute__((address_space(1))) void*)(gp),                     \
      (__attribute__((address_space(3))) void*)(lp), 16, 0, 0)

__device__ __forceinline__ unsigned short f2bf(float f) {
  unsigned u = __builtin_bit_cast(unsigned, f);
  u += 0x7fffu + ((u >> 16) & 1u);   // RNE
  return (unsigned short)(u >> 16);
}

// ---------------- fused fp32 -> bf16 conversion ----------------
__global__ __launch_bounds__(256) void convert_all(
    const float* __restrict__ x, const float* __restrict__ wq,
    const float* __restrict__ wk, const float* __restrict__ wv,
    const float* __restrict__ wo, unsigned short* __restrict__ xb,
    unsigned short* __restrict__ wqkv, unsigned short* __restrict__ wob) {
  const int X4 = (2 * 2048 * 1024) / 4;
  const int W4 = (1024 * 1024) / 4;
  const int total = X4 + 4 * W4;
  for (int i = blockIdx.x * 256 + threadIdx.x; i < total;
       i += gridDim.x * 256) {
    const float* src; unsigned short* dst; int off;
    if (i < X4)               { src = x;  dst = xb;                   off = i; }
    else if (i < X4 + W4)     { src = wq; dst = wqkv;                 off = i - X4; }
    else if (i < X4 + 2 * W4) { src = wk; dst = wqkv + 1024 * 1024;   off = i - X4 - W4; }
    else if (i < X4 + 3 * W4) { src = wv; dst = wqkv + 2 * 1024 * 1024; off = i - X4 - 2 * W4; }
    else                      { src = wo; dst = wob;                  off = i - X4 - 3 * W4; }
    float4 v = ((const float4*)src)[off];
    uint2 o;
    o.x = (unsigned)f2bf(v.x) | ((unsigned)f2bf(v.y) << 16);
    o.y = (unsigned)f2bf(v.z) | ((unsigned)f2bf(v.w) << 16);
    ((uint2*)dst)[off] = o;
  }
}

// ---------------- 128x128 bf16 GEMM, C = A * B^T (m97 structure) ----------------
template <int MODE>
__global__ __launch_bounds__(256, 2) void gemm_bt(
    const unsigned short* __restrict__ A, const unsigned short* __restrict__ Bw,
    unsigned short* __restrict__ o_q, unsigned short* __restrict__ o_k,
    unsigned short* __restrict__ o_vT, const float* __restrict__ bias,
    float* __restrict__ o_f) {
  constexpr int K = 1024;
  __shared__ unsigned short As[128 * 32];
  __shared__ unsigned short Bs[128 * 32];
  const int t = threadIdx.x;
  const int w = t >> 6;
  const int lane = t & 63;
  const int g = lane >> 4;
  const int q16 = lane & 15;
  const int wm = w >> 1, wn = w & 1;
  const int bn0 = blockIdx.x * 128, bm0 = blockIdx.y * 128;
  const int arow = t >> 2;
  const int acol = (t & 3) * 8;

  f32x4 acc[4][4];
  const f32x4 z4 = {0.f, 0.f, 0.f, 0.f};
#pragma unroll
  for (int i = 0; i < 4; ++i)
#pragma unroll
    for (int j = 0; j < 4; ++j) acc[i][j] = z4;

  for (int k0 = 0; k0 < K; k0 += 32) {
#pragma unroll
    for (int c = 0; c < 2; ++c) {
      GLDS16(A + (size_t)(bm0 + c * 64 + arow) * K + k0 + acol,
             As + c * 2048 + w * 512);
      GLDS16(Bw + (size_t)(bn0 + c * 64 + arow) * K + k0 + acol,
             Bs + c * 2048 + w * 512);
    }
    __syncthreads();
    bf16x8 af[4], bf[4];
#pragma unroll
    for (int i = 0; i < 4; ++i)
      af[i] = *(const bf16x8*)(As + (wm * 64 + i * 16 + q16) * 32 + g * 8);
#pragma unroll
    for (int j = 0; j < 4; ++j)
      bf[j] = *(const bf16x8*)(Bs + (wn * 64 + j * 16 + q16) * 32 + g * 8);
#pragma unroll
    for (int i = 0; i < 4; ++i)
#pragma unroll
      for (int j = 0; j < 4; ++j)
        acc[i][j] =
            __builtin_amdgcn_mfma_f32_16x16x32_bf16(af[i], bf[j], acc[i][j], 0, 0, 0);
    __syncthreads();
  }

  if constexpr (MODE == 0) {
    const int which = bn0 >> 10;
#pragma unroll
    for (int i = 0; i < 4; ++i)
#pragma unroll
      for (int j = 0; j < 4; ++j)
#pragma unroll
        for (int r = 0; r < 4; ++r) {
          const int m = bm0 + wm * 64 + i * 16 + g * 4 + r;
          const int n = (bn0 & 1023) + wn * 64 + j * 16 + q16;
          const float v = acc[i][j][r];
          const int bb = m >> 11, lp = m & 2047;
          const int h = n >> 6, d = n & 63;
          const int bh = bb * 16 + h;
          if (which == 0)
            o_q[((size_t)bh * 2048 + lp) * 64 + d] = f2bf(v * 0.125f);
          else if (which == 1)
            o_k[((size_t)bh * 2048 + lp) * 64 + d] = f2bf(v);
          else
            o_vT[((size_t)bh * 64 + d) * 2048 + lp] = f2bf(v);
        }
  } else {
#pragma unroll
    for (int i = 0; i < 4; ++i)
#pragma unroll
      for (int j = 0; j < 4; ++j)
#pragma unroll
        for (int r = 0; r < 4; ++r) {
          const int m = bm0 + wm * 64 + i * 16 + g * 4 + r;
          const int n = bn0 + wn * 64 + j * 16 + q16;
          o_f[(size_t)m * 1024 + n] = acc[i][j][r] + bias[n];
        }
  }
}

// ---------------- flash attention: R6 structure + 1KB-run mask staging -------
// R6 (proven correct, 245us) with ONE change: mask staged as 1KB-contiguous
// row-runs (superstage = 8 kv-tiles, ring-2, 2 rows/wave/tile, uniform issue)
// instead of 128B strips at 8KB stride (the DRAM-granule wall, ~2 TB/s).
// Issue order per tile [M,M,K,V]; K/V stay lead-2 ring-3 (R6). Waits derived:
// steady vmcnt(4) (= R6), superstage boundary vmcnt(2). No wait ever touches
// a young prefetch; all cross-wave reads barrier-protected as in R6.
// LDS 157 KB -> 1 block/CU (4 waves); in-flight 32KB/CU >> 9.2KB needed.
__global__ __launch_bounds__(256, 1) void attn_kernel(
    const unsigned short* __restrict__ kb, const unsigned short* __restrict__ qb,
    const unsigned short* __restrict__ vT, const float* __restrict__ mask,
    unsigned short* __restrict__ hb) {
  __shared__ float Mst[2][64][256];          // 128 KB mask ring (1KB rows)
  __shared__ unsigned short Kst[3 * 2048];   // 12 KB K ring-3 (32kv x 64d)
  __shared__ unsigned short Vst[3 * 2048];   // 12 KB V ring-3 (64d x 32kv)
  __shared__ unsigned short Plds[4][16][40]; // 5 KB P round-trip
  const int orig = blockIdx.x;
  const int bid = (orig & 7) * 128 + (orig >> 3);  // bijective (1024 % 8 == 0)
  const int bh = bid >> 5, qt = bid & 31;
  const int t = threadIdx.x, w = t >> 6, lane = t & 63;
  const int g = lane >> 4, q16 = lane & 15;
  const int qrow0 = qt * 64;
  const int qrow = qrow0 + w * 16;

  const unsigned short* qptr = qb + ((size_t)bh * 2048 + qrow + q16) * 64 + g * 8;
  bf16x8 qf0 = *(const bf16x8*)(qptr);
  bf16x8 qf1 = *(const bf16x8*)(qptr + 32);

  f32x4 O[4];
  const f32x4 z4 = {0.f, 0.f, 0.f, 0.f};
#pragma unroll
  for (int dt = 0; dt < 4; ++dt) O[dt] = z4;
  float mrun = -1e30f, lsum = 0.f;

  // ---- staging sources (pre-swizzled; glds dest = uniform base + lane*16B) --
  // K: wave w stages kv-rows w*8..w*8+7 (8 chunks/row of 8 bf16)  [R6]
  const int rK = w * 8 + (lane >> 3), cK = (lane & 7) ^ (rK & 7);
  const unsigned short* ksrc = kb + (size_t)bh * 2048 * 64 + (size_t)rK * 64 + cK * 8;
  // V^T: wave w stages d-rows w*16..w*16+15 (4 chunks/row of 8 bf16)  [R6]
  const int rV = w * 16 + (lane >> 2), cV = (lane & 3) ^ ((rV >> 1) & 3);
  const unsigned short* vsrc = vT + (size_t)bh * 64 * 2048 + (size_t)rV * 2048 + cV * 8;
  // M: wave w owns q-rows w*16..w*16+15; per tile stage 2 rows' 1KB runs,
  //    XOR-permuted within 128B octets by key = row&7.
  const float* mA = mask + ((size_t)bh * 2048 + qrow0 + w * 16) * 2048;
  const int la = lane & 56, lb = lane & 7;

  // ---- swizzled read offsets (fixed per lane) ----
  const int x7 = q16 & 7;
  const int kx0 = (g ^ x7) * 8;
  const int kx1 = ((g + 4) ^ x7) * 8;
  const int cg0 = (g ^ x7) * 4;
  const int cg1 = ((g + 4) ^ x7) * 4;
  const int vx = (g ^ ((q16 >> 1) & 3)) * 8;

  // ---- prologue: all 16 mask rows of superstage 0, then K0,V0,K1,V1 ----
#pragma unroll
  for (int j = 0; j < 16; ++j)
    GLDS16(mA + (size_t)j * 2048 + (la | (lb ^ (j & 7))) * 4, &Mst[0][w * 16 + j][0]);
  GLDS16(ksrc, Kst + 0 * 2048 + w * 512);
  GLDS16(vsrc, Vst + 0 * 2048 + w * 512);
  GLDS16(ksrc + (size_t)1 * 2048, Kst + 1 * 2048 + w * 512);
  GLDS16(vsrc + (size_t)1 * 32, Vst + 1 * 2048 + w * 512);

  for (int tl = 0; tl < 64; ++tl) {
    const int s = tl >> 3, u = tl & 7;
    // steady: retire [M,M,K,V](tl) issued 2 tiles ago -> vmcnt(4)
    // boundary (u==0): additionally retire the last 2 M rows of this
    // superstage (issued 1 tile ago, before K(tl+1),V(tl+1)) -> vmcnt(2)
    if (u == 0) asm volatile("s_waitcnt vmcnt(2)" ::: "memory");
    else        asm volatile("s_waitcnt vmcnt(4)" ::: "memory");
    __builtin_amdgcn_s_barrier();
    __builtin_amdgcn_sched_barrier(0);

    // ---- STAGE (issue order: M,M,K,V) ----
    {
      const int sn = (s + 1 < 8) ? s + 1 : 7;
      const int r0 = 2 * u, r1 = 2 * u + 1;
      GLDS16(mA + (size_t)r0 * 2048 + sn * 256 + (la | (lb ^ (r0 & 7))) * 4,
             &Mst[(s + 1) & 1][w * 16 + r0][0]);
      GLDS16(mA + (size_t)r1 * 2048 + sn * 256 + (la | (lb ^ (r1 & 7))) * 4,
             &Mst[(s + 1) & 1][w * 16 + r1][0]);
      const int tn = (tl + 2 < 64) ? tl + 2 : 63;
      GLDS16(ksrc + (size_t)tn * 2048, Kst + ((tl + 2) % 3) * 2048 + w * 512);
      GLDS16(vsrc + (size_t)tn * 32, Vst + ((tl + 2) % 3) * 2048 + w * 512);
    }

    const int sb = tl % 3;
    const unsigned short* Kb = Kst + sb * 2048;
    const unsigned short* Vb = Vst + sb * 2048;

    bf16x8 vf[4];
#pragma unroll
    for (int dt = 0; dt < 4; ++dt)
      vf[dt] = *(const bf16x8*)(Vb + (dt * 16 + q16) * 32 + vx);

    bf16x8 kf0 = *(const bf16x8*)(Kb + q16 * 64 + kx0);
    bf16x8 kf1 = *(const bf16x8*)(Kb + q16 * 64 + kx1);
    bf16x8 kf2 = *(const bf16x8*)(Kb + (16 + q16) * 64 + kx0);
    bf16x8 kf3 = *(const bf16x8*)(Kb + (16 + q16) * 64 + kx1);

    f32x4 S0 = z4, S1 = z4;
    S0 = __builtin_amdgcn_mfma_f32_16x16x32_bf16(kf0, qf0, S0, 0, 0, 0);
    S0 = __builtin_amdgcn_mfma_f32_16x16x32_bf16(kf1, qf1, S0, 0, 0, 0);
    S1 = __builtin_amdgcn_mfma_f32_16x16x32_bf16(kf2, qf0, S1, 0, 0, 0);
    S1 = __builtin_amdgcn_mfma_f32_16x16x32_bf16(kf3, qf1, S1, 0, 0, 0);

    {
      const float* Mb = &Mst[s & 1][w * 16 + q16][u * 32];
      S0 += *(const f32x4*)(Mb + cg0);
      S1 += *(const f32x4*)(Mb + cg1);
    }

    // defer-max: lane-local screen; cross-lane reduce + rescale only if needed
    float lmax = fmaxf(fmaxf(fmaxf(S0[0], S0[1]), fmaxf(S0[2], S0[3])),
                       fmaxf(fmaxf(S1[0], S1[1]), fmaxf(S1[2], S1[3])));
    if (!__all(lmax <= mrun + 8.f)) {
      float pm = fmaxf(lmax, __shfl_xor(lmax, 16));
      pm = fmaxf(pm, __shfl_xor(pm, 32));
      const float mnew = fmaxf(mrun, pm);
      const float alpha = __expf(mrun - mnew);
      lsum *= alpha;
      float ar[4];
#pragma unroll
      for (int r = 0; r < 4; ++r) ar[r] = __shfl(alpha, g * 4 + r);
#pragma unroll
      for (int dt = 0; dt < 4; ++dt)
#pragma unroll
        for (int r = 0; r < 4; ++r) O[dt][r] *= ar[r];
      mrun = mnew;
    }

    float p0[4], p1[4], rs = 0.f;
#pragma unroll
    for (int r = 0; r < 4; ++r) {
      p0[r] = __expf(S0[r] - mrun);
      p1[r] = __expf(S1[r] - mrun);
      rs += p0[r] + p1[r];
    }
    lsum += rs;  // per-lane partial; cross-lane reduce deferred to epilogue

    uint2 pw0, pw1;
    pw0.x = (unsigned)f2bf(p0[0]) | ((unsigned)f2bf(p0[1]) << 16);
    pw0.y = (unsigned)f2bf(p0[2]) | ((unsigned)f2bf(p0[3]) << 16);
    pw1.x = (unsigned)f2bf(p1[0]) | ((unsigned)f2bf(p1[1]) << 16);
    pw1.y = (unsigned)f2bf(p1[2]) | ((unsigned)f2bf(p1[3]) << 16);
    *(uint2*)&Plds[w][q16][g * 4] = pw0;
    *(uint2*)&Plds[w][q16][16 + g * 4] = pw1;
    bf16x8 pf = *(const bf16x8*)&Plds[w][q16][g * 8];
#pragma unroll
    for (int dt = 0; dt < 4; ++dt)
      O[dt] = __builtin_amdgcn_mfma_f32_16x16x32_bf16(pf, vf[dt], O[dt], 0, 0, 0);
  }

  // epilogue: reduce per-lane lsum partials across the 4 g-copies of each row
  float rsrow = lsum + __shfl_xor(lsum, 16);
  rsrow += __shfl_xor(rsrow, 32);
  float li[4];
#pragma unroll
  for (int r = 0; r < 4; ++r) li[r] = 1.f / __shfl(rsrow, g * 4 + r);
  const int b = bh >> 4, h = bh & 15;
#pragma unroll
  for (int dt = 0; dt < 4; ++dt)
#pragma unroll
    for (int r = 0; r < 4; ++r) {
      const int qg = qrow + g * 4 + r;
      hb[((size_t)b * 2048 + qg) * 1024 + h * 64 + dt * 16 + q16] =
          f2bf(O[dt][r] * li[r]);
    }
}

extern "C" void kernel_launch(void* const* d_in, const int* in_sizes, int n_in,
                              void* d_out, int out_size, void* d_ws,
                              size_t ws_size, hipStream_t stream) {
  const float* x    = (const float*)d_in[0];
  const float* mask = (const float*)d_in[1];
  const float* wq   = (const float*)d_in[2];
  const float* wk   = (const float*)d_in[3];
  const float* wv   = (const float*)d_in[4];
  const float* wo   = (const float*)d_in[5];
  const float* bo   = (const float*)d_in[6];
  float* out = (float*)d_out;
  char* ws = (char*)d_ws;

  unsigned short* xb   = (unsigned short*)(ws);                        // 8 MiB
  unsigned short* wqkv = (unsigned short*)(ws + 8u * 1024 * 1024);     // 6 MiB
  unsigned short* wob  = (unsigned short*)(ws + 14u * 1024 * 1024);    // 2 MiB
  unsigned short* qbuf = (unsigned short*)(ws + 16u * 1024 * 1024);    // 8 MiB
  unsigned short* kbuf = (unsigned short*)(ws + 24u * 1024 * 1024);    // 8 MiB
  unsigned short* vTb  = (unsigned short*)(ws + 32u * 1024 * 1024);    // 8 MiB
  unsigned short* hb   = (unsigned short*)(ws + 40u * 1024 * 1024);    // 8 MiB
  (void)in_sizes; (void)n_in; (void)out_size; (void)ws_size;

  convert_all<<<2048, 256, 0, stream>>>(x, wq, wk, wv, wo, xb, wqkv, wob);
  gemm_bt<0><<<dim3(24, 32), 256, 0, stream>>>(xb, wqkv, qbuf, kbuf, vTb,
                                               nullptr, nullptr);
  attn_kernel<<<1024, 256, 0, stream>>>(kbuf, qbuf, vTb, mask, hb);
  gemm_bt<1><<<dim3(8, 32), 256, 0, stream>>>(hb, wob, nullptr, nullptr,
                                              nullptr, bo, out);
}

// Round 9
// 258.830 us; speedup vs baseline: 1.4967x; 1.4967x over previous
//
#include <hip/hip_runtime.h>

// Problem constants: B=2, L=2048, D=1024, H=16, DH=64, BH=B*H=32, M=B*L=4096
// SCALE = DH^-0.5 = 0.125 (folded into Q at projection time)

typedef __attribute__((ext_vector_type(8))) short short8;
typedef __attribute__((ext_vector_type(8))) __bf16 bf16x8;
typedef __attribute__((ext_vector_type(4))) float f32x4;

#define GLDS16(gp, lp)                                                         \
  __builtin_amdgcn_global_load_lds(                                            \
      (const __attribute__((address_space(1))) void*)(gp),                     \
      (__attribute__((address_space(3))) void*)(lp), 16, 0, 0)
#define GLDS4(gp, lp)                                                          \
  __builtin_amdgcn_global_load_lds(                                            \
      (const __attribute__((address_space(1))) void*)(gp),                     \
      (__attribute__((address_space(3))) void*)(lp), 4, 0, 0)

__device__ __forceinline__ unsigned short f2bf(float f) {
  unsigned u = __builtin_bit_cast(unsigned, f);
  u += 0x7fffu + ((u >> 16) & 1u);   // RNE
  return (unsigned short)(u >> 16);
}

// ---------------- fused fp32 -> bf16 conversion ----------------
__global__ __launch_bounds__(256) void convert_all(
    const float* __restrict__ x, const float* __restrict__ wq,
    const float* __restrict__ wk, const float* __restrict__ wv,
    const float* __restrict__ wo, unsigned short* __restrict__ xb,
    unsigned short* __restrict__ wqkv, unsigned short* __restrict__ wob) {
  const int X4 = (2 * 2048 * 1024) / 4;
  const int W4 = (1024 * 1024) / 4;
  const int total = X4 + 4 * W4;
  for (int i = blockIdx.x * 256 + threadIdx.x; i < total;
       i += gridDim.x * 256) {
    const float* src; unsigned short* dst; int off;
    if (i < X4)               { src = x;  dst = xb;                   off = i; }
    else if (i < X4 + W4)     { src = wq; dst = wqkv;                 off = i - X4; }
    else if (i < X4 + 2 * W4) { src = wk; dst = wqkv + 1024 * 1024;   off = i - X4 - W4; }
    else if (i < X4 + 3 * W4) { src = wv; dst = wqkv + 2 * 1024 * 1024; off = i - X4 - 2 * W4; }
    else                      { src = wo; dst = wob;                  off = i - X4 - 3 * W4; }
    float4 v = ((const float4*)src)[off];
    uint2 o;
    o.x = (unsigned)f2bf(v.x) | ((unsigned)f2bf(v.y) << 16);
    o.y = (unsigned)f2bf(v.z) | ((unsigned)f2bf(v.w) << 16);
    ((uint2*)dst)[off] = o;
  }
}

// ---------------- 128x128 bf16 GEMM, C = A * B^T (m97 structure) ----------------
template <int MODE>
__global__ __launch_bounds__(256, 2) void gemm_bt(
    const unsigned short* __restrict__ A, const unsigned short* __restrict__ Bw,
    unsigned short* __restrict__ o_q, unsigned short* __restrict__ o_k,
    unsigned short* __restrict__ o_vT, const float* __restrict__ bias,
    float* __restrict__ o_f) {
  constexpr int K = 1024;
  __shared__ unsigned short As[128 * 32];
  __shared__ unsigned short Bs[128 * 32];
  const int t = threadIdx.x;
  const int w = t >> 6;
  const int lane = t & 63;
  const int g = lane >> 4;
  const int q16 = lane & 15;
  const int wm = w >> 1, wn = w & 1;
  const int bn0 = blockIdx.x * 128, bm0 = blockIdx.y * 128;
  const int arow = t >> 2;
  const int acol = (t & 3) * 8;

  f32x4 acc[4][4];
  const f32x4 z4 = {0.f, 0.f, 0.f, 0.f};
#pragma unroll
  for (int i = 0; i < 4; ++i)
#pragma unroll
    for (int j = 0; j < 4; ++j) acc[i][j] = z4;

  for (int k0 = 0; k0 < K; k0 += 32) {
#pragma unroll
    for (int c = 0; c < 2; ++c) {
      GLDS16(A + (size_t)(bm0 + c * 64 + arow) * K + k0 + acol,
             As + c * 2048 + w * 512);
      GLDS16(Bw + (size_t)(bn0 + c * 64 + arow) * K + k0 + acol,
             Bs + c * 2048 + w * 512);
    }
    __syncthreads();
    bf16x8 af[4], bf[4];
#pragma unroll
    for (int i = 0; i < 4; ++i)
      af[i] = *(const bf16x8*)(As + (wm * 64 + i * 16 + q16) * 32 + g * 8);
#pragma unroll
    for (int j = 0; j < 4; ++j)
      bf[j] = *(const bf16x8*)(Bs + (wn * 64 + j * 16 + q16) * 32 + g * 8);
#pragma unroll
    for (int i = 0; i < 4; ++i)
#pragma unroll
      for (int j = 0; j < 4; ++j)
        acc[i][j] =
            __builtin_amdgcn_mfma_f32_16x16x32_bf16(af[i], bf[j], acc[i][j], 0, 0, 0);
    __syncthreads();
  }

  if constexpr (MODE == 0) {
    const int which = bn0 >> 10;
#pragma unroll
    for (int i = 0; i < 4; ++i)
#pragma unroll
      for (int j = 0; j < 4; ++j)
#pragma unroll
        for (int r = 0; r < 4; ++r) {
          const int m = bm0 + wm * 64 + i * 16 + g * 4 + r;
          const int n = (bn0 & 1023) + wn * 64 + j * 16 + q16;
          const float v = acc[i][j][r];
          const int bb = m >> 11, lp = m & 2047;
          const int h = n >> 6, d = n & 63;
          const int bh = bb * 16 + h;
          if (which == 0)
            o_q[((size_t)bh * 2048 + lp) * 64 + d] = f2bf(v * 0.125f);
          else if (which == 1)
            o_k[((size_t)bh * 2048 + lp) * 64 + d] = f2bf(v);
          else
            o_vT[((size_t)bh * 64 + d) * 2048 + lp] = f2bf(v);
        }
  } else {
#pragma unroll
    for (int i = 0; i < 4; ++i)
#pragma unroll
      for (int j = 0; j < 4; ++j)
#pragma unroll
        for (int r = 0; r < 4; ++r) {
          const int m = bm0 + wm * 64 + i * 16 + g * 4 + r;
          const int n = bn0 + wn * 64 + j * 16 + q16;
          o_f[(size_t)m * 1024 + n] = acc[i][j][r] + bias[n];
        }
  }
}

// ---------------- flash attention: R6 + 256B mask runs + 2 blocks/CU ---------
// R6/R8 isolated the two limiters: 128B mask granule caps HBM at ~1.1 TB/s
// (R6); 1-block occupancy caps at ~0.85 TB/s (R8). This round gets both:
// superstage=2 tiles, mask staged as 256B-contiguous runs (size-4 glds, one
// op per row-run, all lead-2), ring-2 = 32KB -> total LDS 61KB -> 2 blocks/CU
// (8 waves/CU, 64KB in flight/CU). Constant 20-op FIFO/wave: even-tile wait
// vmcnt(2), odd-tile vmcnt(18). K/V ring-3 lead-2 exactly as R6.
__global__ __launch_bounds__(256, 2) void attn_kernel(
    const unsigned short* __restrict__ kb, const unsigned short* __restrict__ qb,
    const unsigned short* __restrict__ vT, const float* __restrict__ mask,
    unsigned short* __restrict__ hb) {
  __shared__ float Mst[2][64][64];           // 32 KB mask ring (256B rows)
  __shared__ unsigned short Kst[3 * 2048];   // 12 KB K ring-3 (32kv x 64d)
  __shared__ unsigned short Vst[3 * 2048];   // 12 KB V ring-3 (64d x 32kv)
  __shared__ unsigned short Plds[4][16][40]; // 5 KB P round-trip
  const int orig = blockIdx.x;
  const int bid = (orig & 7) * 128 + (orig >> 3);  // bijective (1024 % 8 == 0)
  const int bh = bid >> 5, qt = bid & 31;
  const int t = threadIdx.x, w = t >> 6, lane = t & 63;
  const int g = lane >> 4, q16 = lane & 15;
  const int qrow0 = qt * 64;
  const int qrow = qrow0 + w * 16;

  const unsigned short* qptr = qb + ((size_t)bh * 2048 + qrow + q16) * 64 + g * 8;
  bf16x8 qf0 = *(const bf16x8*)(qptr);
  bf16x8 qf1 = *(const bf16x8*)(qptr + 32);

  f32x4 O[4];
  const f32x4 z4 = {0.f, 0.f, 0.f, 0.f};
#pragma unroll
  for (int dt = 0; dt < 4; ++dt) O[dt] = z4;
  float mrun = -1e30f, lsum = 0.f;

  // ---- staging sources (pre-swizzled; glds dest = uniform base + lane*sz) ---
  // K: wave w stages kv-rows w*8..w*8+7 (8 chunks/row of 8 bf16)  [R6]
  const int rK = w * 8 + (lane >> 3), cK = (lane & 7) ^ (rK & 7);
  const unsigned short* ksrc = kb + (size_t)bh * 2048 * 64 + (size_t)rK * 64 + cK * 8;
  // V^T: wave w stages d-rows w*16..w*16+15 (4 chunks/row of 8 bf16)  [R6]
  const int rV = w * 16 + (lane >> 2), cV = (lane & 3) ^ ((rV >> 1) & 3);
  const unsigned short* vsrc = vT + (size_t)bh * 64 * 2048 + (size_t)rV * 2048 + cV * 8;
  // M: wave w owns q-rows w*16..w*16+15. One size-4 glds = one row's 256B run
  // (2 tiles of kv). Chunk-XOR pre-swizzle within each 128B octet (key=row&7).
  const float* mA = mask + ((size_t)bh * 2048 + qrow0 + w * 16) * 2048;
  const int mo_oct = (lane >> 5) & 1;  // 16B-chunk octet within the 256B run
  const int mo_k = (lane >> 2) & 7;    // chunk within octet
  const int mo_j = lane & 3;           // f32 within chunk

  // ---- swizzled read offsets (fixed per lane) ----
  const int x7 = q16 & 7;
  const int kx0 = (g ^ x7) * 8;
  const int kx1 = ((g + 4) ^ x7) * 8;
  const int cg0 = (g ^ x7) * 4;
  const int cg1 = ((g + 4) ^ x7) * 4;
  const int vx = (g ^ ((q16 >> 1) & 3)) * 8;

  // stage all 16 mask rows (superstage sidx) into buffer dstbuf - 16 glds
#define STAGE_M(sidx, dstbuf)                                                  \
  do {                                                                         \
    _Pragma("unroll") for (int jr = 0; jr < 16; ++jr) {                        \
      GLDS4(mA + (size_t)jr * 2048 + (sidx)*64 +                               \
                (mo_oct * 8 + (mo_k ^ (jr & 7))) * 4 + mo_j,                   \
            &Mst[dstbuf][w * 16 + jr][0]);                                     \
    }                                                                          \
  } while (0)

  // ---- prologue (mirrors steady state): [K0,V0,M(s0)x16], [K1,V1] ----
  GLDS16(ksrc, Kst + 0 * 2048 + w * 512);
  GLDS16(vsrc, Vst + 0 * 2048 + w * 512);
  STAGE_M(0, 0);
  GLDS16(ksrc + (size_t)1 * 2048, Kst + 1 * 2048 + w * 512);
  GLDS16(vsrc + (size_t)1 * 32, Vst + 1 * 2048 + w * 512);

  for (int tl = 0; tl < 64; ++tl) {
    const int s = tl >> 1, u = tl & 1;
    // constant 20-op FIFO/wave: even tile retires [K,V,Mx16](oldest 18),
    // odd tile retires [K,V](oldest 2). Lead-2 for every op.
    if (u == 0) asm volatile("s_waitcnt vmcnt(2)" ::: "memory");
    else        asm volatile("s_waitcnt vmcnt(18)" ::: "memory");
    __builtin_amdgcn_s_barrier();
    __builtin_amdgcn_sched_barrier(0);

    // ---- STAGE: K,V lead-2 (ring-3); even tiles also next mask superstage --
    {
      const int tn = (tl + 2 < 64) ? tl + 2 : 63;
      GLDS16(ksrc + (size_t)tn * 2048, Kst + ((tl + 2) % 3) * 2048 + w * 512);
      GLDS16(vsrc + (size_t)tn * 32, Vst + ((tl + 2) % 3) * 2048 + w * 512);
      if (u == 0) {
        const int sn = (s + 1 < 32) ? s + 1 : 31;
        STAGE_M(sn, (s + 1) & 1);
      }
    }

    const int sb = tl % 3;
    const unsigned short* Kb = Kst + sb * 2048;
    const unsigned short* Vb = Vst + sb * 2048;

    bf16x8 vf[4];
#pragma unroll
    for (int dt = 0; dt < 4; ++dt)
      vf[dt] = *(const bf16x8*)(Vb + (dt * 16 + q16) * 32 + vx);

    bf16x8 kf0 = *(const bf16x8*)(Kb + q16 * 64 + kx0);
    bf16x8 kf1 = *(const bf16x8*)(Kb + q16 * 64 + kx1);
    bf16x8 kf2 = *(const bf16x8*)(Kb + (16 + q16) * 64 + kx0);
    bf16x8 kf3 = *(const bf16x8*)(Kb + (16 + q16) * 64 + kx1);

    f32x4 S0 = z4, S1 = z4;
    S0 = __builtin_amdgcn_mfma_f32_16x16x32_bf16(kf0, qf0, S0, 0, 0, 0);
    S0 = __builtin_amdgcn_mfma_f32_16x16x32_bf16(kf1, qf1, S0, 0, 0, 0);
    S1 = __builtin_amdgcn_mfma_f32_16x16x32_bf16(kf2, qf0, S1, 0, 0, 0);
    S1 = __builtin_amdgcn_mfma_f32_16x16x32_bf16(kf3, qf1, S1, 0, 0, 0);

    {
      const float* Mrow = &Mst[s & 1][w * 16 + q16][u * 32];
      S0 += *(const f32x4*)(Mrow + cg0);
      S1 += *(const f32x4*)(Mrow + cg1);
    }

    // defer-max: lane-local screen; cross-lane reduce + rescale only if needed
    float lmax = fmaxf(fmaxf(fmaxf(S0[0], S0[1]), fmaxf(S0[2], S0[3])),
                       fmaxf(fmaxf(S1[0], S1[1]), fmaxf(S1[2], S1[3])));
    if (!__all(lmax <= mrun + 8.f)) {
      float pm = fmaxf(lmax, __shfl_xor(lmax, 16));
      pm = fmaxf(pm, __shfl_xor(pm, 32));
      const float mnew = fmaxf(mrun, pm);
      const float alpha = __expf(mrun - mnew);
      lsum *= alpha;
      float ar[4];
#pragma unroll
      for (int r = 0; r < 4; ++r) ar[r] = __shfl(alpha, g * 4 + r);
#pragma unroll
      for (int dt = 0; dt < 4; ++dt)
#pragma unroll
        for (int r = 0; r < 4; ++r) O[dt][r] *= ar[r];
      mrun = mnew;
    }

    float p0[4], p1[4], rs = 0.f;
#pragma unroll
    for (int r = 0; r < 4; ++r) {
      p0[r] = __expf(S0[r] - mrun);
      p1[r] = __expf(S1[r] - mrun);
      rs += p0[r] + p1[r];
    }
    lsum += rs;  // per-lane partial; cross-lane reduce deferred to epilogue

    uint2 pw0, pw1;
    pw0.x = (unsigned)f2bf(p0[0]) | ((unsigned)f2bf(p0[1]) << 16);
    pw0.y = (unsigned)f2bf(p0[2]) | ((unsigned)f2bf(p0[3]) << 16);
    pw1.x = (unsigned)f2bf(p1[0]) | ((unsigned)f2bf(p1[1]) << 16);
    pw1.y = (unsigned)f2bf(p1[2]) | ((unsigned)f2bf(p1[3]) << 16);
    *(uint2*)&Plds[w][q16][g * 4] = pw0;
    *(uint2*)&Plds[w][q16][16 + g * 4] = pw1;
    bf16x8 pf = *(const bf16x8*)&Plds[w][q16][g * 8];
#pragma unroll
    for (int dt = 0; dt < 4; ++dt)
      O[dt] = __builtin_amdgcn_mfma_f32_16x16x32_bf16(pf, vf[dt], O[dt], 0, 0, 0);
  }
#undef STAGE_M

  // epilogue: reduce per-lane lsum partials across the 4 g-copies of each row
  float rsrow = lsum + __shfl_xor(lsum, 16);
  rsrow += __shfl_xor(rsrow, 32);
  float li[4];
#pragma unroll
  for (int r = 0; r < 4; ++r) li[r] = 1.f / __shfl(rsrow, g * 4 + r);
  const int b = bh >> 4, h = bh & 15;
#pragma unroll
  for (int dt = 0; dt < 4; ++dt)
#pragma unroll
    for (int r = 0; r < 4; ++r) {
      const int qg = qrow + g * 4 + r;
      hb[((size_t)b * 2048 + qg) * 1024 + h * 64 + dt * 16 + q16] =
          f2bf(O[dt][r] * li[r]);
    }
}

extern "C" void kernel_launch(void* const* d_in, const int* in_sizes, int n_in,
                              void* d_out, int out_size, void* d_ws,
                              size_t ws_size, hipStream_t stream) {
  const float* x    = (const float*)d_in[0];
  const float* mask = (const float*)d_in[1];
  const float* wq   = (const float*)d_in[2];
  const float* wk   = (const float*)d_in[3];
  const float* wv   = (const float*)d_in[4];
  const float* wo   = (const float*)d_in[5];
  const float* bo   = (const float*)d_in[6];
  float* out = (float*)d_out;
  char* ws = (char*)d_ws;

  unsigned short* xb   = (unsigned short*)(ws);                        // 8 MiB
  unsigned short* wqkv = (unsigned short*)(ws + 8u * 1024 * 1024);     // 6 MiB
  unsigned short* wob  = (unsigned short*)(ws + 14u * 1024 * 1024);    // 2 MiB
  unsigned short* qbuf = (unsigned short*)(ws + 16u * 1024 * 1024);    // 8 MiB
  unsigned short* kbuf = (unsigned short*)(ws + 24u * 1024 * 1024);    // 8 MiB
  unsigned short* vTb  = (unsigned short*)(ws + 32u * 1024 * 1024);    // 8 MiB
  unsigned short* hb   = (unsigned short*)(ws + 40u * 1024 * 1024);    // 8 MiB
  (void)in_sizes; (void)n_in; (void)out_size; (void)ws_size;

  convert_all<<<2048, 256, 0, stream>>>(x, wq, wk, wv, wo, xb, wqkv, wob);
  gemm_bt<0><<<dim3(24, 32), 256, 0, stream>>>(xb, wqkv, qbuf, kbuf, vTb,
                                               nullptr, nullptr);
  attn_kernel<<<1024, 256, 0, stream>>>(kbuf, qbuf, vTb, mask, hb);
  gemm_bt<1><<<dim3(8, 32), 256, 0, stream>>>(hb, wob, nullptr, nullptr,
                                              nullptr, bo, out);
}